// Round 6
// baseline (757.852 us; speedup 1.0000x reference)
//
#include <hip/hip_runtime.h>
#include <cstdint>
#include <cstddef>

typedef _Float16 half8 __attribute__((ext_vector_type(8)));
typedef __fp16 fp16x2 __attribute__((ext_vector_type(2)));
typedef float f32x16 __attribute__((ext_vector_type(16)));
typedef float f32x4 __attribute__((ext_vector_type(4)));
typedef float f32x2 __attribute__((ext_vector_type(2)));

// ---------------- hf8 decode (scalar, f32) ----------------
// code: sign(1) | e(4, bias 7) | m(3). e==0 -> m * 2^-9 ; else (1+m/8)*2^(e-7).
// Bit-identical to OCP e4m3fn except 0x7F/0xFF (|x|=480 vs NaN) — unreachable
// for this problem's data (|w| <= ~0.16).
__device__ __forceinline__ float dec_hf8(unsigned c) {
    unsigned e = (c >> 3) & 0xFu;
    unsigned m = c & 7u;
    float normal = __uint_as_float(((e + 120u) << 23) | (m << 20));
    float sub = (float)m * 0x1p-9f;
    float mag = (e != 0u) ? normal : sub;
    return (c & 0x80u) ? -mag : mag;
}

// decode 8 e4m3 codes (two packed words) -> 8 fp16, exact
__device__ __forceinline__ half8 dec8(unsigned w0, unsigned w1) {
#if __has_builtin(__builtin_amdgcn_cvt_pk_f32_fp8) && __has_builtin(__builtin_amdgcn_cvt_pkrtz)
    f32x2 a0 = __builtin_amdgcn_cvt_pk_f32_fp8((int)w0, false);
    f32x2 a1 = __builtin_amdgcn_cvt_pk_f32_fp8((int)w0, true);
    f32x2 a2 = __builtin_amdgcn_cvt_pk_f32_fp8((int)w1, false);
    f32x2 a3 = __builtin_amdgcn_cvt_pk_f32_fp8((int)w1, true);
    fp16x2 h0 = __builtin_amdgcn_cvt_pkrtz(a0.x, a0.y);  // exact: e4m3 subset of f16
    fp16x2 h1 = __builtin_amdgcn_cvt_pkrtz(a1.x, a1.y);
    fp16x2 h2 = __builtin_amdgcn_cvt_pkrtz(a2.x, a2.y);
    fp16x2 h3 = __builtin_amdgcn_cvt_pkrtz(a3.x, a3.y);
    half8 r = {(_Float16)h0.x, (_Float16)h0.y, (_Float16)h1.x, (_Float16)h1.y,
               (_Float16)h2.x, (_Float16)h2.y, (_Float16)h3.x, (_Float16)h3.y};
    return r;
#else
    half8 r;
#pragma unroll
    for (int i = 0; i < 4; ++i) r[i] = (_Float16)dec_hf8((w0 >> (8 * i)) & 0xFFu);
#pragma unroll
    for (int i = 0; i < 4; ++i) r[4 + i] = (_Float16)dec_hf8((w1 >> (8 * i)) & 0xFFu);
    return r;
#endif
}

// ---------------- prep: decode W codes int32 -> fp16 ----------------
__global__ __launch_bounds__(256) void decode_w(const int* __restrict__ codes,
                                                _Float16* __restrict__ out,
                                                long long n16) {
    long long i = (long long)blockIdx.x * 256 + threadIdx.x;
    if (i >= n16) return;
    long long base = i * 16;
    unsigned w[4];
#pragma unroll
    for (int q = 0; q < 4; ++q) {
        int4 c = *(const int4*)(codes + base + q * 4);
        w[q] = ((unsigned)c.x & 255u) | (((unsigned)c.y & 255u) << 8) |
               (((unsigned)c.z & 255u) << 16) | (((unsigned)c.w & 255u) << 24);
    }
    *(half8*)(out + base) = dec8(w[0], w[1]);
    *(half8*)(out + base + 8) = dec8(w[2], w[3]);
}

// ---------------- prep (old path): repack weight codes int32 -> uint8 ----------------
__global__ __launch_bounds__(256) void repack_codes(const int* __restrict__ codes,
                                                    unsigned* __restrict__ out,
                                                    long long n16) {
    long long i = (long long)blockIdx.x * 256 + threadIdx.x;
    if (i >= n16) return;
    long long base = i * 16;
    unsigned w[4];
#pragma unroll
    for (int q = 0; q < 4; ++q) {
        int4 c = *(const int4*)(codes + base + q * 4);
        w[q] = ((unsigned)c.x & 255u) | (((unsigned)c.y & 255u) << 8) |
               (((unsigned)c.z & 255u) << 16) | (((unsigned)c.w & 255u) << 24);
    }
    *(uint4*)(out + i * 4) = make_uint4(w[0], w[1], w[2], w[3]);
}

// ---------------- prep: X fp32 -> fp16 ----------------
__global__ __launch_bounds__(256) void cvt_x(const float* __restrict__ X,
                                             _Float16* __restrict__ out,
                                             long long n8) {
    long long i = (long long)blockIdx.x * 256 + threadIdx.x;
    if (i >= n8) return;
    long long base = i * 8;
    float4 v0 = *(const float4*)(X + base);
    float4 v1 = *(const float4*)(X + base + 4);
    half8 h = {(_Float16)v0.x, (_Float16)v0.y, (_Float16)v0.z, (_Float16)v0.w,
               (_Float16)v1.x, (_Float16)v1.y, (_Float16)v1.z, (_Float16)v1.w};
    *(half8*)(out + base) = h;
}

// ---------------- async global->LDS (16B/lane, wave-uniform LDS base) ----------------
__device__ __forceinline__ void gl_lds16(const void* g, void* l) {
    __builtin_amdgcn_global_load_lds(
        (__attribute__((address_space(1))) void*)(g),
        (__attribute__((address_space(3))) void*)(l), 16, 0, 0);
}

// legacy swizzle for the fallback kernel
#define FKEY(r) (((r) ^ ((r) >> 3)) & 7)

// raw barrier (no vmcnt/lgkm drain) + compiler memory fence both sides
#define BAR()                                  \
    {                                          \
        asm volatile("" ::: "memory");         \
        __builtin_amdgcn_s_barrier();          \
        asm volatile("" ::: "memory");         \
    }

// ============ m201-template 256x256 GEMM (16x16x32, 8-phase, st_16x32) ============
// C = Xh[M][K] * Wh[N][K]^T + bias. BK=64; 2 K-tiles per iter (u even -> parity 0,
// v=u+1 -> parity 1). 8 waves (2m x 4n), wave tile 128x64; phase = one wave-quadrant
// (MH,NH = 64x32) x K=64 = 16 mfma_f32_16x16x32_f16. Register-held frags:
// reads/K-tile = {12,4,8,0} ds_read_b128 (A half read at ph1 AND ph3!).
// LDS 128KB: As/Bs [parity][half][128 rows][64 f16].
// st_16x32 swizzle: 16B-chunk ^= ((row>>2)&1)<<1, applied BOTH sides (pre-swizzled
// gl_lds source chunk + swizzled ds_read chunk). Verified involution-consistent.
//
// ROUND-6 FIX (round 5 raced, absmax 9.4): stage slots re-derived from read
// lifetimes. Region -> last read -> stage slot (one STG per phase):
//   Bs[0][0] ph2 -> ph3(u+2) ; Bs[0][1] ph2 -> ph4(u+2)
//   As[0][0] ph3 -> ph5(u+2) ; As[0][1] ph3 -> ph6(u+2)
//   Bs[1][0] ph6 -> ph7(v+2) ; Bs[1][1] ph6 -> ph8(v+2)
//   As[1][0] ph7 -> NEXT iter ph1(v) ; As[1][1] ph7 -> NEXT iter ph2(v)
// (round 5 staged A halves at ph2/ph6, overwriting rows 64-127 BEFORE their
// MH=1 read at ph3/ph7 — the race.) Every stage now sits >=1 certifying barrier
// after its region's last reader (each read phase: lgkmcnt(0) -> MFMA -> BAR).
// In-flight ledger (STG = 2 loads, FIFO vmcnt):
//   steady W4 (end ph4): outstanding = ph7,ph8(prev) + ph1..ph4 = 12 loads;
//     vmcnt(4) completes 8 oldest = B1h0,B1h1,A1h0,A1h1 of tile v -> ph5 safe.
//   steady W8 (end ph8): outstanding = ph3,ph4 + ph5..ph8 = 12; vmcnt(4)
//     completes ph3..ph6 = all 4 parity-0 halves of tile u+2 -> next ph1 safe.
//   prologue: 6 STG {B0h0,B0h1,A0h0,A0h1(t0); B1h0,B1h1(t1)}; vmcnt(4) lands t0.
//   tail (!more): ph3-ph8 stages off; W4 = vmcnt(0) (8 outstanding); W8 none.
//   kIters even (K%128==0) -> v+2 guard == u+2 guard.
__global__ __launch_bounds__(512) void hgemm_p8(const _Float16* __restrict__ Xh,
                                                const _Float16* __restrict__ Wh,
                                                const int* __restrict__ bias_codes,
                                                float* __restrict__ C,
                                                int M, int N, int K) {
    __shared__ _Float16 As[2][2][128 * 64];
    __shared__ _Float16 Bs[2][2][128 * 64];

    const int tid  = threadIdx.x;
    const int lane = tid & 63;
    const int wid  = tid >> 6;

    const int nT = N >> 8;
    const int mT = M >> 8;
    int mTile, nTile;
    int bid = blockIdx.x;
    if (mT == 16) {                  // XCD map: XCD x owns m-band {2x,2x+1} x all n
        int x = bid & 7;
        int l = bid >> 3;
        mTile = (x << 1) + (l & 1);
        nTile = l >> 1;
    } else {
        mTile = bid / nT;
        nTile = bid % nT;
    }
    const int mB = mTile << 8;
    const int nB = nTile << 8;
    const int kIters = K >> 6;       // even, >= 2 (launcher guarantees K % 128 == 0)

    // ---- staging: thread stages rows srow, srow+64 of a half-tile; source chunk
    // pre-swizzled so linear gl_lds dest yields swizzled LDS layout.
    const int    srow = tid >> 3;
    const int    sg   = (tid & 7) ^ (((srow >> 2) & 1) << 1);  // st_16x32 inverse
    const size_t soff = (size_t)srow * K + ((size_t)sg << 3);
    const size_t rowStep = (size_t)K << 6;   // +64 rows; row-bit2 unchanged -> same swz
    const _Float16* aS0 = Xh + (size_t)mB * K + soff;
    const _Float16* aS1 = Xh + (size_t)(mB + 128) * K + soff;
    const _Float16* bS0 = Wh + (size_t)nB * K + soff;
    const _Float16* bS1 = Wh + (size_t)(nB + 128) * K + soff;

#define STG(SRC, LDSP, tt)                                            \
    {                                                                 \
        char* d_ = (char*)(LDSP);                                     \
        const _Float16* s_ = (SRC) + ((size_t)(tt) << 6);             \
        gl_lds16(s_, d_ + (tid << 4));                                \
        gl_lds16(s_ + rowStep, d_ + ((512 + tid) << 4));              \
    }

    // ---- fragment geometry (16x16x32: A/B row = lane&15, k-chunk = lane>>4 + kk*4)
    const int wm  = wid >> 2;                    // A-half used by this wave
    const int wn  = wid & 3;
    const int bh  = wn >> 1;                     // B-half used by this wave
    const int l15 = lane & 15;
    const int l4  = lane >> 4;
    const int swz = ((l15 >> 2) & 1) << 1;       // row-bit2 of all frag rows == l15 bit2
    const int coff0 = ((l4 ^ swz) << 3);         // kk=0 chunk offset (f16 units)
    const int coff1 = (((4 + l4) ^ swz) << 3);   // kk=1
    const int bRow = ((wn & 1) << 6) + l15;

    half8 a[4][2], b[2][2][2];
    f32x4 acc[2][4][2][2] = {};  // [MH][mf][NH][nf]

#define RD_A(BASE, MH)                                                          \
    _Pragma("unroll") for (int mf = 0; mf < 4; ++mf) {                          \
        const _Float16* p_ = (BASE) + ((((MH) << 6) + (mf << 4) + l15) << 6);   \
        a[mf][0] = *(const half8*)(p_ + coff0);                                 \
        a[mf][1] = *(const half8*)(p_ + coff1);                                 \
    }

#define RD_B(BASE, NH)                                                          \
    _Pragma("unroll") for (int nf = 0; nf < 2; ++nf) {                          \
        const _Float16* p_ = (BASE) + ((((NH) << 5) + (nf << 4) + bRow) << 6);  \
        b[NH][nf][0] = *(const half8*)(p_ + coff0);                             \
        b[NH][nf][1] = *(const half8*)(p_ + coff1);                             \
    }

#define MFMA_PH(MH, NH)                                                         \
    {                                                                           \
        __builtin_amdgcn_s_setprio(1);                                          \
        _Pragma("unroll") for (int kk = 0; kk < 2; ++kk)                        \
        _Pragma("unroll") for (int mf = 0; mf < 4; ++mf)                        \
        _Pragma("unroll") for (int nf = 0; nf < 2; ++nf)                        \
            acc[MH][mf][NH][nf] = __builtin_amdgcn_mfma_f32_16x16x32_f16(       \
                a[mf][kk], b[NH][nf][kk], acc[MH][mf][NH][nf], 0, 0, 0);        \
        __builtin_amdgcn_s_setprio(0);                                          \
    }

#define LGKM0                                              \
    {                                                      \
        asm volatile("s_waitcnt lgkmcnt(0)" ::: "memory"); \
        __builtin_amdgcn_sched_barrier(0);                 \
    }
#define VMC(n) asm volatile("s_waitcnt vmcnt(" #n ")" ::: "memory")

    // ---- prologue: tile0 all 4 halves + tile1 {B0,B1}; land tile0 (vmcnt(4))
    STG(bS0, &Bs[0][0][0], 0);
    STG(bS1, &Bs[0][1][0], 0);
    STG(aS0, &As[0][0][0], 0);
    STG(aS1, &As[0][1][0], 0);
    STG(bS0, &Bs[1][0][0], 1);
    STG(bS1, &Bs[1][1][0], 1);
    VMC(4);
    BAR();

    for (int u = 0; u < kIters; u += 2) {
        const int v = u + 1;
        const bool more = (u + 2 < kIters);
        const _Float16* A0 = &As[0][wm][0];
        const _Float16* B0 = &Bs[0][bh][0];
        const _Float16* A1 = &As[1][wm][0];
        const _Float16* B1 = &Bs[1][bh][0];

        // ---------- K-tile u (parity 0) ----------
        RD_A(A0, 0); RD_B(B0, 0);                       // ph1: 12 reads
        STG(aS0, &As[1][0][0], v);                      //   A1h0(v): last read ph7(prev)
        BAR(); LGKM0; MFMA_PH(0, 0); BAR();

        RD_B(B0, 1);                                    // ph2: 4 reads
        STG(aS1, &As[1][1][0], v);                      //   A1h1(v): last read ph7(prev)
        BAR(); LGKM0; MFMA_PH(0, 1); BAR();

        RD_A(A0, 1);                                    // ph3: 8 reads (A0 rows 64-127!)
        if (more) STG(bS0, &Bs[0][0][0], u + 2);        //   B0h0: last read ph2
        BAR(); LGKM0; MFMA_PH(1, 0); BAR();

        if (more) STG(bS1, &Bs[0][1][0], u + 2);        // ph4: 0 reads; B0h1: last ph2
        BAR(); MFMA_PH(1, 1);
        if (more) { VMC(4); } else { VMC(0); }          // tile v fully landed
        BAR();

        // ---------- K-tile v (parity 1) ----------
        RD_A(A1, 0); RD_B(B1, 0);                       // ph5: 12 reads
        if (more) STG(aS0, &As[0][0][0], u + 2);        //   A0h0: last read ph3
        BAR(); LGKM0; MFMA_PH(0, 0); BAR();

        RD_B(B1, 1);                                    // ph6: 4 reads
        if (more) STG(aS1, &As[0][1][0], u + 2);        //   A0h1: last read ph3
        BAR(); LGKM0; MFMA_PH(0, 1); BAR();

        RD_A(A1, 1);                                    // ph7: 8 reads (A1 rows 64-127)
        if (more) STG(bS0, &Bs[1][0][0], v + 2);        //   B1h0: last read ph6
        BAR(); LGKM0; MFMA_PH(1, 0); BAR();

        if (more) STG(bS1, &Bs[1][1][0], v + 2);        // ph8: 0 reads; B1h1: last ph6
        BAR(); MFMA_PH(1, 1);
        if (more) VMC(4);                               // tile u+2 fully landed
        BAR();
    }

#undef STG
#undef RD_A
#undef RD_B
#undef MFMA_PH
#undef LGKM0
#undef VMC

    // ---- epilogue: 16x16 C/D map: col = lane&15, row = (lane>>4)*4 + reg [m89]
#pragma unroll
    for (int NH = 0; NH < 2; ++NH)
#pragma unroll
        for (int nf = 0; nf < 2; ++nf) {
            const int col = nB + (wn << 6) + (NH << 5) + (nf << 4) + l15;
            const float bv = dec_hf8((unsigned)bias_codes[col]);
#pragma unroll
            for (int MH = 0; MH < 2; ++MH)
#pragma unroll
                for (int mf = 0; mf < 4; ++mf) {
                    const int rbase = mB + (wm << 7) + (MH << 6) + (mf << 4) + (l4 << 2);
#pragma unroll
                    for (int r = 0; r < 4; ++r)
                        C[(size_t)(rbase + r) * N + col] = acc[MH][mf][NH][nf][r] + bv;
                }
        }
}

// ================= fallback GEMM (verified kernel, 128x256 tile) =========
__global__ __launch_bounds__(512) void hgemm_x2(const _Float16* __restrict__ Xh,
                                                const unsigned char* __restrict__ W8,
                                                const int* __restrict__ bias_codes,
                                                float* __restrict__ C,
                                                int M, int N, int K) {
    __shared__ _Float16 As[128 * 64];
    __shared__ _Float16 Bs[256 * 64];

    const int tid  = threadIdx.x;
    const int lane = tid & 63;
    const int wid  = tid >> 6;

    const int nT = N >> 8;
    const int mT = M >> 7;
    int mTile, nTile;
    int bid = blockIdx.x;
    if (mT == 32) {
        int x = bid & 7;
        int l = bid >> 3;
        mTile = (x << 2) + (l & 3);
        nTile = l >> 2;
    } else {
        mTile = bid / nT;
        nTile = bid % nT;
    }
    const int mB = mTile << 7;
    const int nB = nTile << 8;

    const int kIters = K >> 6;

    const _Float16* aptr[2];
#pragma unroll
    for (int it = 0; it < 2; ++it) {
        int p = it * 512 + tid;
        int row = p >> 3;
        int g = (p & 7) ^ FKEY(row);
        aptr[it] = Xh + (size_t)(mB + row) * K + (g << 3);
    }
    char* as_base = (char*)As;

    const int brow = tid >> 1;
    const int bhc  = tid & 1;
    const unsigned char* bptr = W8 + (size_t)(nB + brow) * K + (bhc << 5);
    const int bfk = FKEY(brow);
    _Float16* brow_lds = Bs + (brow << 6);
    const int bg0 = bhc << 2;

    const int wm = (wid >> 2) << 6;
    const int wn = (wid & 3) << 6;
    const int fr = lane & 31;
    const int kh = lane >> 5;
    const int fkey = FKEY(fr);

    f32x16 acc[2][2] = {};

    for (int kt = 0; kt < kIters; ++kt) {
#pragma unroll
        for (int it = 0; it < 2; ++it) {
            gl_lds16(aptr[it], as_base + ((it * 512 + tid) << 4));
            aptr[it] += 64;
        }
        uint4 q0 = *(const uint4*)(bptr);
        uint4 q1 = *(const uint4*)(bptr + 16);
        bptr += 64;
        half8 d0 = dec8(q0.x, q0.y);
        half8 d1 = dec8(q0.z, q0.w);
        half8 d2 = dec8(q1.x, q1.y);
        half8 d3 = dec8(q1.z, q1.w);
        *(half8*)(brow_lds + (((bg0 + 0) ^ bfk) << 3)) = d0;
        *(half8*)(brow_lds + (((bg0 + 1) ^ bfk) << 3)) = d1;
        *(half8*)(brow_lds + (((bg0 + 2) ^ bfk) << 3)) = d2;
        *(half8*)(brow_lds + (((bg0 + 3) ^ bfk) << 3)) = d3;
        __syncthreads();

#pragma unroll
        for (int ks = 0; ks < 4; ++ks) {
            const int lc = (ks << 1) + kh;
            half8 a[2], bb[2];
#pragma unroll
            for (int i = 0; i < 2; ++i) {
                const int co = ((lc ^ fkey ^ (i << 2)) << 3);
                a[i]  = *(const half8*)(As + ((wm + (i << 5) + fr) << 6) + co);
                bb[i] = *(const half8*)(Bs + ((wn + (i << 5) + fr) << 6) + co);
            }
#pragma unroll
            for (int mi = 0; mi < 2; ++mi)
#pragma unroll
                for (int ni = 0; ni < 2; ++ni)
                    acc[mi][ni] = __builtin_amdgcn_mfma_f32_32x32x16_f16(
                        a[mi], bb[ni], acc[mi][ni], 0, 0, 0);
        }
        __syncthreads();
    }

#pragma unroll
    for (int ni = 0; ni < 2; ++ni) {
        int col = nB + wn + (ni << 5) + fr;
        float bv = dec_hf8((unsigned)bias_codes[col]);
#pragma unroll
        for (int mi = 0; mi < 2; ++mi) {
            int rbase = mB + wm + (mi << 5) + (kh << 2);
#pragma unroll
            for (int r = 0; r < 16; ++r) {
                int row = rbase + (r & 3) + ((r >> 2) << 3);
                C[(size_t)row * N + col] = acc[mi][ni][r] + bv;
            }
        }
    }
}

// ---------------- correctness parachute ----------------
__global__ void naive_kernel(const float* __restrict__ X, const int* __restrict__ Wc,
                             const int* __restrict__ Bc, float* __restrict__ C,
                             int M, int N, int K) {
    long long idx = (long long)blockIdx.x * 256 + threadIdx.x;
    if (idx >= (long long)M * N) return;
    int m = (int)(idx / N);
    int n = (int)(idx % N);
    float s = dec_hf8((unsigned)Bc[n]);
    const float* x = X + (size_t)m * K;
    const int* w = Wc + (size_t)n * K;
    for (int k = 0; k < K; ++k) s += x[k] * dec_hf8((unsigned)w[k]);
    C[idx] = s;
}

extern "C" void kernel_launch(void* const* d_in, const int* in_sizes, int n_in,
                              void* d_out, int out_size, void* d_ws, size_t ws_size,
                              hipStream_t stream) {
    const float* X  = (const float*)d_in[0];   // x: fp16 promoted to fp32 by harness
    const int*   Wc = (const int*)d_in[1];     // weight codes as int32
    const int*   Bc = (const int*)d_in[2];     // bias codes as int32
    float* C = (float*)d_out;

    long long wn = (long long)in_sizes[1];     // D_OUT * D_IN
    int N = in_sizes[2];                       // D_OUT
    int K = (int)(wn / N);                     // D_IN
    long long xn = (long long)in_sizes[0];
    int M = (int)(xn / K);                     // B*S

    size_t needXh = (size_t)xn * sizeof(_Float16);
    size_t needWh = (size_t)wn * sizeof(_Float16);
    size_t needW8 = (size_t)wn;

    bool ok8 = (M % 256 == 0) && (N % 256 == 0) && (K % 128 == 0) &&
               (wn % 16 == 0) && (xn % 8 == 0) &&
               (ws_size >= ((needXh + 15) & ~(size_t)15) + needWh + 16);
    bool okOld = (M % 128 == 0) && (N % 256 == 0) && (K % 64 == 0) &&
                 (wn % 16 == 0) && (xn % 8 == 0) &&
                 (ws_size >= needW8 + needXh + 16);

    if (ok8) {
        _Float16* Xh = (_Float16*)d_ws;
        _Float16* Wh = (_Float16*)((char*)d_ws + ((needXh + 15) & ~(size_t)15));
        cvt_x<<<dim3((unsigned)((xn / 8 + 255) / 256)), dim3(256), 0, stream>>>(X, Xh, xn / 8);
        decode_w<<<dim3((unsigned)((wn / 16 + 255) / 256)), dim3(256), 0, stream>>>(
            Wc, Wh, wn / 16);
        unsigned blocks = (unsigned)((M / 256) * (N / 256));
        hgemm_p8<<<dim3(blocks), dim3(512), 0, stream>>>(Xh, Wh, Bc, C, M, N, K);
    } else if (okOld) {
        unsigned char* W8 = (unsigned char*)d_ws;
        _Float16* Xh = (_Float16*)((char*)d_ws + ((needW8 + 15) & ~(size_t)15));
        repack_codes<<<dim3((unsigned)((wn / 16 + 255) / 256)), dim3(256), 0, stream>>>(
            Wc, (unsigned*)W8, wn / 16);
        cvt_x<<<dim3((unsigned)((xn / 8 + 255) / 256)), dim3(256), 0, stream>>>(X, Xh, xn / 8);
        unsigned blocks = (unsigned)((M / 128) * (N / 256));
        hgemm_x2<<<dim3(blocks), dim3(512), 0, stream>>>(Xh, W8, Bc, C, M, N, K);
    } else {
        long long total = (long long)M * N;
        naive_kernel<<<dim3((unsigned)((total + 255) / 256)), dim3(256), 0, stream>>>(
            X, Wc, Bc, C, M, N, K);
    }
}